// Round 8
// baseline (621.784 us; speedup 1.0000x reference)
//
#include <hip/hip_runtime.h>
#include <hip/hip_bf16.h>
#include <stdint.h>

// Encoder: B=2,S=2048,D=1024,HID=1024,NH=16,C=64,L=4. 4096 token-rows.
#define TOK 4096
#define DM  1024

using u16 = unsigned short;
typedef __attribute__((ext_vector_type(8))) short short8;   // bf16x8 frag (4 VGPR)
typedef __attribute__((ext_vector_type(4))) float f32x4;

__device__ __forceinline__ u16 f2bf(float f){
  unsigned u = __float_as_uint(f);
  return (u16)((u + 0x7fffu + ((u >> 16) & 1u)) >> 16);   // RNE
}
__device__ __forceinline__ float bf2f(u16 h){ return __uint_as_float(((unsigned)h) << 16); }

// raw hardware exp2 / rcp (skip OCML guards; args are range-safe here; 2^-200
// flushes to 0 which implements the causal mask).
__device__ __forceinline__ float fexp2(float x){
#if __has_builtin(__builtin_amdgcn_exp2f)
  return __builtin_amdgcn_exp2f(x);
#else
  float r; asm("v_exp_f32 %0, %1\n\ts_nop 0" : "=v"(r) : "v"(x)); return r;
#endif
}
__device__ __forceinline__ float frcp(float x){
#if __has_builtin(__builtin_amdgcn_rcpf)
  return __builtin_amdgcn_rcpf(x);
#else
  float r; asm("v_rcp_f32 %0, %1\n\ts_nop 0" : "=v"(r) : "v"(x)); return r;
#endif
}

// ---------------- pos-enc add: r = x + pe, xb = bf16(r) ----------------
__global__ __launch_bounds__(256) void posenc_add(
    const float* __restrict__ x, float* __restrict__ r, u16* __restrict__ xb)
{
  const int t = blockIdx.x;          // token row 0..4095
  const int s = t & 2047;            // seq position
  const size_t base = (size_t)t * DM;
#pragma unroll
  for (int i = 0; i < 4; ++i){
    const int d = threadIdx.x + i * 256;
    const float e = (float)(d & ~1) * (1.0f / (float)DM);
    const float denom = powf(1000.0f, e);
    const float mat = (float)s / denom;
    const float pe = (d & 1) ? cosf(mat) : sinf(mat);
    const float v = x[base + d] + pe;
    r[base + d] = v;
    xb[base + d] = f2bf(v);
  }
}

// ---------- weight transpose+cast: 6 matrices [1024][1024] f32 -> [N][K] bf16 ----------
// WT layout per layer: [0]=WqT [1]=WkT [2]=WvT [3]=WoT [4]=W1T [5]=W2T
// Multi-layer launch: bid = (l-l0)*6144 + mm*1024 + t
__global__ __launch_bounds__(256) void transpose6(
    const float* __restrict__ Wq, const float* __restrict__ Wk, const float* __restrict__ Wv,
    const float* __restrict__ Wo, const float* __restrict__ W1, const float* __restrict__ W2,
    u16* __restrict__ WT, int l0)
{
  __shared__ float tile[32][33];
  const int bid = blockIdx.x;
  const int l  = l0 + bid / 6144;          // layer spans 6144 blocks
  const int mm = (bid >> 10) % 6;          // matrix 0..5 within layer
  const int t  = bid & 1023;
  const int tn = (t & 31) * 32;
  const int tk = (t >> 5) * 32;
  const float* src = (mm==0)?Wq:(mm==1)?Wk:(mm==2)?Wv:(mm==3)?Wo:(mm==4)?W1:W2;
  src += (size_t)l * 1048576;
  u16* dst = WT + ((size_t)(l - l0) * 6 + mm) * 1048576;
  const int tx = threadIdx.x & 31, ty = threadIdx.x >> 5;
#pragma unroll
  for (int i = 0; i < 4; ++i)
    tile[ty + i*8][tx] = src[(size_t)(tk + ty + i*8) * 1024 + tn + tx];
  __syncthreads();
#pragma unroll
  for (int i = 0; i < 4; ++i)
    dst[(size_t)(tn + ty + i*8) * 1024 + tk + tx] = f2bf(tile[tx][ty + i*8]);
}

#define BM 128
#define BK 64
#define KD 1024

// ---------------- fused qkv GEMM + channel attention ----------------
// Block = 128 tokens x 1 head. 8 waves (512 thr). GEMM tile 128x192:
// cols 0-63 = q(head h), 64-127 = k, 128-191 = v; B rows come from
// WqT/WkT/WvT rows [h*64, h*64+64). Epilogue writes bias'd bf16 q*0.125,k,v
// into LDS [128][200] (aliases staging bufs after final barrier), then each
// wave runs channel-attention for 16 tokens (2-token ILP) and writes av.
#define QS 200   // u16 stride of QKV LDS row (192 data + 8 pad; 400B, 16B-aligned)

__global__ __launch_bounds__(512, 4) void qkv_attn(
    const u16* __restrict__ A, const u16* __restrict__ WTq,
    const float* __restrict__ bq, const float* __restrict__ bk, const float* __restrict__ bv,
    u16* __restrict__ av)
{
  __shared__ __align__(16) u16 lds[128 * QS];     // 51.2 KB
  u16* sA = lds;                                  // [128][64] bf16 (16 KB)
  u16* sB = lds + 8192;                           // [192][64] bf16 (24 KB)
  const int tid  = threadIdx.x;
  const int lane = tid & 63;
  const int wave = tid >> 6;                      // 0..7
  // grid 512 = 32 tokblocks x 16 heads; bijective XCD swizzle; head fastest
  const int nwg = gridDim.x;
  const int wg  = (blockIdx.x & 7) * (nwg >> 3) + (blockIdx.x >> 3);
  const int h   = wg & 15;
  const int t0  = (wg >> 4) * BM;

  // staging geometry (pre-swizzled source, linear LDS dest; row&7 == srow)
  const int srow  = lane >> 3;
  const int sslot = (lane & 7) ^ srow;
  // A chunks c = wave*2+p (16 chunks of 8 rows)
  const u16* gA = A + (size_t)(t0 + wave*16 + srow) * KD + sslot * 8;
  u16* lA = sA + (wave*2) * 512;                  // 512 u16 per 8-row chunk
  // B chunks c = wave*3+p (24 chunks); matrix = c>>3, rows h*64+(c&7)*8+srow
  const int c0 = wave * 3;
  const u16* gB0 = WTq + (size_t)((c0+0)>>3)*1048576 + (size_t)(h*64 + ((c0+0)&7)*8 + srow)*KD + sslot*8;
  const u16* gB1 = WTq + (size_t)((c0+1)>>3)*1048576 + (size_t)(h*64 + ((c0+1)&7)*8 + srow)*KD + sslot*8;
  const u16* gB2 = WTq + (size_t)((c0+2)>>3)*1048576 + (size_t)(h*64 + ((c0+2)&7)*8 + srow)*KD + sslot*8;
  u16* lB0 = sB + (c0+0) * 512;
  u16* lB1 = sB + (c0+1) * 512;
  u16* lB2 = sB + (c0+2) * 512;

  const int wr = wave >> 2;        // 0..1 (64-row band)
  const int wc = wave & 3;         // 0..3 (48-col band)
  f32x4 acc[4][3] = {};

  for (int kt = 0; kt < KD/BK; ++kt){
    const int k0 = kt * BK;
#pragma unroll
    for (int p = 0; p < 2; ++p)
      __builtin_amdgcn_global_load_lds(
          (const __attribute__((address_space(1))) void*)(gA + p*8*KD + k0),
          (__attribute__((address_space(3))) void*)(lA + p*512), 16, 0, 0);
    __builtin_amdgcn_global_load_lds(
        (const __attribute__((address_space(1))) void*)(gB0 + k0),
        (__attribute__((address_space(3))) void*)lB0, 16, 0, 0);
    __builtin_amdgcn_global_load_lds(
        (const __attribute__((address_space(1))) void*)(gB1 + k0),
        (__attribute__((address_space(3))) void*)lB1, 16, 0, 0);
    __builtin_amdgcn_global_load_lds(
        (const __attribute__((address_space(1))) void*)(gB2 + k0),
        (__attribute__((address_space(3))) void*)lB2, 16, 0, 0);
    __syncthreads();
#pragma unroll
    for (int kk = 0; kk < 2; ++kk){
      short8 af[4], bfr[3];
      const int kidx = kk*4 + (lane >> 4);
#pragma unroll
      for (int i = 0; i < 4; ++i){
        const int arow = wr*64 + i*16 + (lane & 15);
        af[i] = *(const short8*)(sA + arow*64 + (kidx ^ (arow & 7)) * 8);
      }
#pragma unroll
      for (int j = 0; j < 3; ++j){
        const int brow = wc*48 + j*16 + (lane & 15);
        bfr[j] = *(const short8*)(sB + brow*64 + (kidx ^ (brow & 7)) * 8);
      }
#pragma unroll
      for (int i = 0; i < 4; ++i)
#pragma unroll
        for (int j = 0; j < 3; ++j)
          acc[i][j] = __builtin_amdgcn_mfma_f32_16x16x32_bf16(af[i], bfr[j], acc[i][j], 0, 0, 0);
    }
    __syncthreads();   // after this in the last iter, sA/sB are dead -> alias
  }

  // epilogue: acc -> QKV LDS as bf16. C/D map: col=lane&15, row=(lane>>4)*4+r.
#pragma unroll
  for (int i = 0; i < 4; ++i){
    const int row = wr*64 + i*16 + (lane >> 4) * 4;
#pragma unroll
    for (int j = 0; j < 3; ++j){
      const int col = wc*48 + j*16 + (lane & 15);
      float bias;                       // segment is uniform per (wc,j)
      if (col < 64)       bias = bq[h*64 + col];
      else if (col < 128) bias = bk[h*64 + col - 64];
      else                bias = bv[h*64 + col - 128];
      const bool isq = (col < 64);
#pragma unroll
      for (int r = 0; r < 4; ++r){
        float v = acc[i][j][r] + bias;
        if (isq) v *= 0.125f;
        lds[(row + r) * QS + col] = f2bf(v);
      }
    }
  }
  __syncthreads();

  // attention: wave handles tokens [wave*16, wave*16+16), 2 at a time (ILP).
  const int r3 = lane & 3;
  for (int tt = 0; tt < 16; tt += 2){
    const int ta = wave*16 + tt;
    const u16* rowa = lds + ta * QS;
    const u16* rowb = rowa + QS;
    const float qa = bf2f(rowa[lane]) * 1.44269504f;
    const float qb = bf2f(rowb[lane]) * 1.44269504f;
    float sa = 0.f, aa = 0.f, sb = 0.f, ab = 0.f;
#pragma unroll
    for (int j0 = 0; j0 < 64; j0 += 8){
      const short8 ka = *(const short8*)(rowa + 64 + j0);
      const short8 va = *(const short8*)(rowa + 128 + j0);
      const short8 kb = *(const short8*)(rowb + 64 + j0);
      const short8 vb = *(const short8*)(rowb + 128 + j0);
      const float bias0 = (j0 + 3 <= lane) ? 0.0f : -200.0f;   // per-quad causal
      const float bias1 = (j0 + 7 <= lane) ? 0.0f : -200.0f;
#pragma unroll
      for (int q = 0; q < 8; ++q){
        const float bias = (q < 4) ? bias0 : bias1;
        const float ea = fexp2(fmaf(qa, bf2f((u16)ka[q]), bias));
        const float eb = fexp2(fmaf(qb, bf2f((u16)kb[q]), bias));
        sa += ea; aa = fmaf(ea, bf2f((u16)va[q]), aa);
        sb += eb; ab = fmaf(eb, bf2f((u16)vb[q]), ab);
      }
    }
    // fixup: lanes with r3<3 are missing j = lane-r3 .. lane
#pragma unroll
    for (int s = 0; s < 3; ++s){
      const int jj = lane - r3 + s;
      const float bias = (s <= r3 && r3 < 3) ? 0.0f : -200.0f;
      const float ea = fexp2(fmaf(qa, bf2f(rowa[64 + jj]), bias));
      const float eb = fexp2(fmaf(qb, bf2f(rowb[64 + jj]), bias));
      sa += ea; aa = fmaf(ea, bf2f(rowa[128 + jj]), aa);
      sb += eb; ab = fmaf(eb, bf2f(rowb[128 + jj]), ab);
    }
    av[(size_t)(t0 + ta)     * DM + h*64 + lane] = f2bf(aa * frcp(sa));
    av[(size_t)(t0 + ta + 1) * DM + h*64 + lane] = f2bf(ab * frcp(sb));
  }
}

// ---------------- bf16 MFMA GEMM: C[M][N] = A[M][1024] @ BT[N][1024]^T ----------------
// m97 structure; BNt=64: grid 512 => 2 blocks/CU. MODE 0: +bias ; MODE 1: relu(+bias)
template<int MODE, int BNt>
__global__ __launch_bounds__(256) void gemm_k1024(
    const u16* __restrict__ A, const u16* __restrict__ BT,
    const float* __restrict__ bias0,
    u16* __restrict__ outB, int M, int N)
{
  constexpr int NFR = BNt / 32;
  __shared__ __align__(16) u16 sA[BM*BK];
  __shared__ __align__(16) u16 sB[BNt*BK];
  const int tid  = threadIdx.x;
  const int lane = tid & 63;
  const int wave = tid >> 6;
  const int nbn = N / BNt;
  const int nwg = gridDim.x;
  const int wg  = (blockIdx.x & 7) * (nwg >> 3) + (blockIdx.x >> 3);
  const size_t m0 = (size_t)(wg / nbn) * BM;
  const size_t n0 = (size_t)(wg % nbn) * BNt;

  const int srow  = lane >> 3;
  const int sslot = (lane & 7) ^ srow;
  const u16* gA = A  + (m0 + wave*32 + srow) * KD + sslot * 8;
  const u16* gB = BT + (n0 + wave*(BNt/4) + srow) * KD + sslot * 8;
  u16* lA = sA + (wave*32) * 64;
  u16* lB = sB + (wave*(BNt/4)) * 64;

  const int wm = (wave >> 1) * 64;
  const int wn = (wave & 1) * (BNt/2);
  f32x4 acc[4][NFR] = {};

  for (int kt = 0; kt < KD/BK; ++kt){
    const int k0 = kt * BK;
#pragma unroll
    for (int p = 0; p < 4; ++p)
      __builtin_amdgcn_global_load_lds(
          (const __attribute__((address_space(1))) void*)(gA + p*8*KD + k0),
          (__attribute__((address_space(3))) void*)(lA + p*8*64), 16, 0, 0);
#pragma unroll
    for (int p = 0; p < BNt/32; ++p)
      __builtin_amdgcn_global_load_lds(
          (const __attribute__((address_space(1))) void*)(gB + p*8*KD + k0),
          (__attribute__((address_space(3))) void*)(lB + p*8*64), 16, 0, 0);
    __syncthreads();
#pragma unroll
    for (int kk = 0; kk < 2; ++kk){
      short8 af[4], bfr[NFR];
      const int kidx = kk*4 + (lane >> 4);
#pragma unroll
      for (int i = 0; i < 4; ++i){
        const int arow = wm + i*16 + (lane & 15);
        af[i]  = *(const short8*)(sA + arow*64 + (kidx ^ (arow & 7)) * 8);
      }
#pragma unroll
      for (int j = 0; j < NFR; ++j){
        const int brow = wn + j*16 + (lane & 15);
        bfr[j] = *(const short8*)(sB + brow*64 + (kidx ^ (brow & 7)) * 8);
      }
#pragma unroll
      for (int i = 0; i < 4; ++i)
#pragma unroll
        for (int j = 0; j < NFR; ++j)
          acc[i][j] = __builtin_amdgcn_mfma_f32_16x16x32_bf16(af[i], bfr[j], acc[i][j], 0, 0, 0);
    }
    __syncthreads();
  }

#pragma unroll
  for (int i = 0; i < 4; ++i){
    const int growb = wm + i*16 + (lane >> 4) * 4;
#pragma unroll
    for (int j = 0; j < NFR; ++j){
      const size_t gcol = n0 + wn + j*16 + (lane & 15);
      const float bv = bias0[gcol];
#pragma unroll
      for (int r = 0; r < 4; ++r){
        const size_t grow = m0 + growb + r;
        float v = acc[i][j][r] + bv;
        if constexpr (MODE == 1) v = fmaxf(v, 0.0f);
        outB[grow * N + gcol] = f2bf(v);
      }
    }
  }
}

// ---------------- residual add + LayerNorm (row of 1024), y in bf16 ----------------
__global__ __launch_bounds__(256) void residual_ln(
    const u16* __restrict__ y, const float* xres,
    const float* __restrict__ gamma, const float* __restrict__ beta,
    float* xout, u16* __restrict__ xb)
{
  __shared__ float red[4];
  const int row = blockIdx.x, tid = threadIdx.x;
  const int lane = tid & 63, wave = tid >> 6;
  const ushort4 a = ((const ushort4*)(y + (size_t)row*DM))[tid];
  const float4  b = ((const float4*)(xres + (size_t)row*DM))[tid];
  float4 s; s.x=bf2f(a.x)+b.x; s.y=bf2f(a.y)+b.y; s.z=bf2f(a.z)+b.z; s.w=bf2f(a.w)+b.w;
  float p = s.x + s.y + s.z + s.w;
#pragma unroll
  for (int o = 32; o; o >>= 1) p += __shfl_xor(p, o);
  if (lane == 0) red[wave] = p;
  __syncthreads();
  const float mu = (red[0]+red[1]+red[2]+red[3]) * (1.0f/(float)DM);
  __syncthreads();
  const float dx=s.x-mu, dy=s.y-mu, dz=s.z-mu, dw=s.w-mu;
  float q2 = dx*dx + dy*dy + dz*dz + dw*dw;
#pragma unroll
  for (int o = 32; o; o >>= 1) q2 += __shfl_xor(q2, o);
  if (lane == 0) red[wave] = q2;
  __syncthreads();
  const float var = (red[0]+red[1]+red[2]+red[3]) * (1.0f/(float)DM);
  const float rstd = rsqrtf(var + 1e-5f);
  const float4 g  = ((const float4*)gamma)[tid];
  const float4 be = ((const float4*)beta)[tid];
  float4 o4;
  o4.x = dx*rstd*g.x + be.x;
  o4.y = dy*rstd*g.y + be.y;
  o4.z = dz*rstd*g.z + be.z;
  o4.w = dw*rstd*g.w + be.w;
  ((float4*)(xout + (size_t)row*DM))[tid] = o4;
  ushort4 ob; ob.x=f2bf(o4.x); ob.y=f2bf(o4.y); ob.z=f2bf(o4.z); ob.w=f2bf(o4.w);
  ((ushort4*)(xb + (size_t)row*DM))[tid] = ob;
}

// ---------------------------------------------------------------------------
extern "C" void kernel_launch(void* const* d_in, const int* in_sizes, int n_in,
                              void* d_out, int out_size, void* d_ws, size_t ws_size,
                              hipStream_t stream)
{
  const float* x    = (const float*)d_in[0];
  const float* Wq   = (const float*)d_in[1];
  const float* bq   = (const float*)d_in[2];
  const float* Wk   = (const float*)d_in[3];
  const float* bk   = (const float*)d_in[4];
  const float* Wv   = (const float*)d_in[5];
  const float* bv   = (const float*)d_in[6];
  const float* Wo   = (const float*)d_in[7];
  const float* bo   = (const float*)d_in[8];
  const float* W1   = (const float*)d_in[9];
  const float* b1   = (const float*)d_in[10];
  const float* W2   = (const float*)d_in[11];
  const float* b2   = (const float*)d_in[12];
  const float* gam  = (const float*)d_in[13];
  const float* bet  = (const float*)d_in[14];

  char* ws = (char*)d_ws;
  size_t off = 0;
  auto alloc = [&](size_t b){ void* p = ws + off; off = (off + b + 255) & ~(size_t)255; return p; };

  const size_t oneWT = 6ull*1048576*2;
  const size_t rest  = ((size_t)TOK*DM*4)   // res
                     + ((size_t)TOK*DM*2)   // xb
                     + ((size_t)TOK*DM*2)   // avb
                     + ((size_t)TOK*DM*2)   // hbuf
                     + ((size_t)TOK*DM*2)   // ybuf
                     + 4096;
  const bool all4 = (4*oneWT + rest) <= ws_size;

  u16*   WT   = (u16*)  alloc(all4 ? 4*oneWT : oneWT);
  float* res  = (float*)alloc((size_t)TOK*DM*4);
  u16*   xb   = (u16*)  alloc((size_t)TOK*DM*2);
  u16*   avb  = (u16*)  alloc((size_t)TOK*DM*2);
  u16*   hbuf = (u16*)  alloc((size_t)TOK*DM*2);
  u16*   ybuf = (u16*)  alloc((size_t)TOK*DM*2);
  if (off > ws_size) return;  // insufficient scratch -> fail loudly (poisoned d_out)

  posenc_add<<<TOK, 256, 0, stream>>>(x, res, xb);
  if (all4)
    transpose6<<<4*6*1024, 256, 0, stream>>>(Wq, Wk, Wv, Wo, W1, W2, WT, 0);

  for (int l = 0; l < 4; ++l){
    u16* wt = all4 ? (WT + (size_t)l * 6 * 1048576) : WT;
    if (!all4)
      transpose6<<<6*1024, 256, 0, stream>>>(Wq, Wk, Wv, Wo, W1, W2, WT, l);
    // fused q,k,v GEMM + channel attention -> avb
    qkv_attn<<<(TOK/BM)*16, 512, 0, stream>>>(
        xb, wt, bq + l*1024, bk + l*1024, bv + l*1024, avb);
    // attn_out = av@Wo+bo -> bf16
    gemm_k1024<0,64><<<(TOK/BM)*(1024/64), 256, 0, stream>>>(
        avb, wt + 3ull*1048576, bo + l*1024, ybuf, TOK, 1024);
    residual_ln<<<TOK, 256, 0, stream>>>(ybuf, res, gam + l*1024, bet + l*1024, res, xb);
    // h = relu(x@W1+b1) -> bf16
    gemm_k1024<1,64><<<(TOK/BM)*(1024/64), 256, 0, stream>>>(
        xb, wt + 4ull*1048576, b1 + l*1024, hbuf, TOK, 1024);
    // y = h@W2+b2 -> bf16
    gemm_k1024<0,64><<<(TOK/BM)*(1024/64), 256, 0, stream>>>(
        hbuf, wt + 5ull*1048576, b2 + l*1024, ybuf, TOK, 1024);
    float* xdst = (l == 3) ? (float*)d_out : res;
    residual_ln<<<TOK, 256, 0, stream>>>(ybuf, res, gam + l*1024, bet + l*1024, xdst, xb);
  }
}